// Round 12
// baseline (263.605 us; speedup 1.0000x reference)
//
#include <hip/hip_runtime.h>
#include <math.h>

typedef __attribute__((ext_vector_type(8))) short bf16x8;
typedef __attribute__((ext_vector_type(8))) unsigned short u16x8;
typedef __attribute__((ext_vector_type(4))) float f32x4;

__device__ __forceinline__ float lrelu(float x) { return x > 0.f ? x : 0.2f * x; }

__device__ __forceinline__ unsigned short f2bf(float f) {
  unsigned int u = __float_as_uint(f);
  unsigned int r = (u + 0x7FFFu + ((u >> 16) & 1u)) >> 16;   // RNE
  return (unsigned short)r;
}
__device__ __forceinline__ float bf2f(unsigned short h) {
  return __uint_as_float(((unsigned int)h) << 16);
}

// swizzled LDS offset (in shorts) for [rows][64]bf16 tile: 16B chunk c16 of row
__device__ __forceinline__ int swz(int row, int c16) {
  return (row * 8 + (c16 ^ (row & 7))) * 8;
}

// ---------------- prep: W1/W2 split+transpose + zero hist partials ----------------
__global__ __launch_bounds__(256) void k_prep(const float* __restrict__ W1,
    const float* __restrict__ W2,
    unsigned short* __restrict__ Wth, unsigned short* __restrict__ Wtl,
    unsigned short* __restrict__ W2th, unsigned short* __restrict__ W2tl,
    int* __restrict__ zeros, int nz)
{
  int bid = blockIdx.x, t = threadIdx.x;
  if (bid < 256) {
    float v = W1[t * 256 + bid];
    unsigned short h = f2bf(v);
    Wth[bid * 256 + t] = h;
    Wtl[bid * 256 + t] = f2bf(v - bf2f(h));
  } else {
    int nn = bid - 256;
    float v = W2[t * 32 + nn];
    unsigned short h = f2bf(v);
    W2th[nn * 256 + t] = h;
    W2tl[nn * 256 + t] = f2bf(v - bf2f(h));
  }
  for (int i = bid * 256 + t; i < nz; i += gridDim.x * 256) zeros[i] = 0;
}

// ---------------- CSR: atomic-free histogram (node-range x edge-slice, LDS bins) ----------------
// grid = NRG*8; block (rg, s): counts slice-s edges landing in node range [rg*1024, +1024)
__global__ __launch_bounds__(1024) void k_hist(const int* __restrict__ ei,
    int* __restrict__ part, int E, int etot, int esl)
{
  __shared__ int bins[1024];
  const int rg = blockIdx.x >> 3, s = blockIdx.x & 7;
  const int t = threadIdx.x;
  bins[t] = 0;
  __syncthreads();
  const unsigned rbeg = rg << 10;
  const int sbeg = s * esl;
  const int send = min(etot, sbeg + esl);
  for (int e = sbeg + t; e < send; e += 1024) {
    int dst = (e < E) ? ei[E + e] : (e - E);
    unsigned loc = (unsigned)dst - rbeg;
    if (loc < 1024u) atomicAdd(&bins[loc], 1);
  }
  __syncthreads();
  part[(size_t)blockIdx.x * 1024 + t] = bins[t];
}

// ---------------- scan1: per-node slice prefix (in-place) + per-block exclusive scan ----------------
__global__ __launch_bounds__(1024) void k_scan1(int* __restrict__ part,
    int* __restrict__ rowptr, int* __restrict__ bsums, int n)
{
  __shared__ int sm[2][1024];
  int t = threadIdx.x, b = blockIdx.x;
  int i = b * 1024 + t;
  // slice exclusive prefix over the 8 partials of node i; total = degree
  int run = 0;
#pragma unroll
  for (int s = 0; s < 8; ++s) {
    size_t idx = (size_t)(b * 8 + s) * 1024 + t;
    int v = part[idx];
    part[idx] = run;
    run += v;
  }
  int v = (i < n) ? run : 0;
  sm[0][t] = v;
  __syncthreads();
  int pb = 0;
  for (int off = 1; off < 1024; off <<= 1) {
    int x = sm[pb][t];
    if (t >= off) x += sm[pb][t - off];
    sm[pb ^ 1][t] = x;
    pb ^= 1;
    __syncthreads();
  }
  if (i < n) rowptr[i] = sm[pb][t] - v;
  if (t == 1023) bsums[b] = sm[pb][1023];
}

__global__ void k_scan23(int* __restrict__ rowptr, const int* __restrict__ bsums,
                         int n, int etot)
{
  int i = blockIdx.x * blockDim.x + threadIdx.x;
  if (i > n) return;
  int b = i >> 10;
  int pre = 0;
  for (int k = 0; k < b; ++k) pre += bsums[k];
  if (i < n) rowptr[i] += pre;
  if (i == 0) rowptr[n] = etot;
}

// ---------------- fill: LDS cursors only (no global atomics) ----------------
__global__ __launch_bounds__(1024) void k_fill(const int* __restrict__ ei,
    const int* __restrict__ rowptr, const int* __restrict__ part,
    int* __restrict__ csrsrc, int E, int etot, int esl)
{
  __shared__ int cur[1024];
  __shared__ int soff[1024];
  const int rg = blockIdx.x >> 3, s = blockIdx.x & 7;
  const int t = threadIdx.x;
  cur[t] = 0;
  soff[t] = part[(size_t)blockIdx.x * 1024 + t];
  __syncthreads();
  const unsigned rbeg = rg << 10;
  const int sbeg = s * esl;
  const int send = min(etot, sbeg + esl);
  for (int e = sbeg + t; e < send; e += 1024) {
    int dst = (e < E) ? ei[E + e] : (e - E);
    unsigned loc = (unsigned)dst - rbeg;
    if (loc < 1024u) {
      int src = (e < E) ? ei[e] : dst;
      int pos = rowptr[dst] + soff[loc] + atomicAdd(&cur[loc], 1);
      csrsrc[pos] = src;
    }
  }
}

// ---------------- GEMM1: BM=64, wave-per-head, full-line epilogue stores ----------------
__global__ __launch_bounds__(512, 4) void k_gemm1(
    const float* __restrict__ X,
    const unsigned short* __restrict__ Bth, const unsigned short* __restrict__ Btl,
    const float* __restrict__ a_src, const float* __restrict__ a_dst,
    unsigned short* __restrict__ h1b, float* __restrict__ as1, float* __restrict__ ad1,
    int M)
{
  __shared__ __align__(16) unsigned short Ah[64 * 64];    // 8KB
  __shared__ __align__(16) unsigned short Al[64 * 64];    // 8KB
  __shared__ __align__(16) unsigned short Cex[8 * 1024];  // 16KB (epilogue, waves 4-7)
  const int t = threadIdx.x;
  const int lane = t & 63;
  const int w = t >> 6;               // wave = head
  const int lrow = lane & 15, lkb = lane >> 4;
  const int brow = blockIdx.x * 64;

  f32x4 acc[4][2];
#pragma unroll
  for (int i = 0; i < 4; ++i)
#pragma unroll
    for (int j = 0; j < 2; ++j) acc[i][j] = (f32x4){0.f, 0.f, 0.f, 0.f};

  float4 pref[2];
#pragma unroll
  for (int r = 0; r < 2; ++r) {
    int id = r * 512 + t, m = id >> 4, cq = id & 15, gm = brow + m;
    pref[r] = (gm < M) ? *(const float4*)&X[(size_t)gm * 256 + cq * 4]
                       : make_float4(0.f, 0.f, 0.f, 0.f);
  }

  for (int kt = 0; kt < 4; ++kt) {
    const int k0 = kt * 64;
#pragma unroll
    for (int r = 0; r < 2; ++r) {
      int id = r * 512 + t, m = id >> 4, cq = id & 15;
      float4 v = pref[r];
      unsigned short h0 = f2bf(v.x), h1 = f2bf(v.y), h2 = f2bf(v.z), h3 = f2bf(v.w);
      unsigned short l0 = f2bf(v.x - bf2f(h0)), l1 = f2bf(v.y - bf2f(h1));
      unsigned short l2 = f2bf(v.z - bf2f(h2)), l3 = f2bf(v.w - bf2f(h3));
      int off = swz(m, cq >> 1) + (cq & 1) * 4;
      *(uint2*)&Ah[off] = make_uint2((unsigned)h0 | ((unsigned)h1 << 16),
                                     (unsigned)h2 | ((unsigned)h3 << 16));
      *(uint2*)&Al[off] = make_uint2((unsigned)l0 | ((unsigned)l1 << 16),
                                     (unsigned)l2 | ((unsigned)l3 << 16));
    }
    if (kt < 3) {
#pragma unroll
      for (int r = 0; r < 2; ++r) {
        int id = r * 512 + t, m = id >> 4, cq = id & 15, gm = brow + m;
        pref[r] = (gm < M) ? *(const float4*)&X[(size_t)gm * 256 + k0 + 64 + cq * 4]
                           : make_float4(0.f, 0.f, 0.f, 0.f);
      }
    }
    __syncthreads();
#pragma unroll
    for (int kk = 0; kk < 2; ++kk) {
      bf16x8 bh[2], bl[2];
#pragma unroll
      for (int j = 0; j < 2; ++j) {
        size_t g = (size_t)(w * 32 + j * 16 + lrow) * 256 + k0 + kk * 32 + lkb * 8;
        bh[j] = *(const bf16x8*)&Bth[g];
        bl[j] = *(const bf16x8*)&Btl[g];
      }
#pragma unroll
      for (int i = 0; i < 4; ++i) {
        int row = i * 16 + lrow;
        int lo = swz(row, kk * 4 + lkb);
        bf16x8 ah = *(const bf16x8*)&Ah[lo];
        bf16x8 al = *(const bf16x8*)&Al[lo];
#pragma unroll
        for (int j = 0; j < 2; ++j) {
          acc[i][j] = __builtin_amdgcn_mfma_f32_16x16x32_bf16(ah, bh[j], acc[i][j], 0, 0, 0);
          acc[i][j] = __builtin_amdgcn_mfma_f32_16x16x32_bf16(ah, bl[j], acc[i][j], 0, 0, 0);
          acc[i][j] = __builtin_amdgcn_mfma_f32_16x16x32_bf16(al, bh[j], acc[i][j], 0, 0, 0);
        }
      }
    }
    __syncthreads();
  }

  const int c15 = lane & 15, q = lane >> 4;

  // fused as1/ad1 for head w, interleaved [n][8]
  float asv[2], adv[2];
#pragma unroll
  for (int j = 0; j < 2; ++j) {
    int idx = w * 32 + j * 16 + c15;
    asv[j] = a_src[idx];
    adv[j] = a_dst[idx];
  }
#pragma unroll
  for (int i = 0; i < 4; ++i) {
#pragma unroll
    for (int r = 0; r < 4; ++r) {
      int gm = brow + i * 16 + q * 4 + r;
      float pS = acc[i][0][r] * asv[0] + acc[i][1][r] * asv[1];
      float pD = acc[i][0][r] * adv[0] + acc[i][1][r] * adv[1];
#pragma unroll
      for (int off = 1; off < 16; off <<= 1) {
        pS += __shfl_xor(pS, off);
        pD += __shfl_xor(pD, off);
      }
      if (c15 == 0 && gm < M) {
        as1[(size_t)gm * 8 + w] = pS;
        ad1[(size_t)gm * 8 + w] = pD;
      }
    }
  }

  // one-pass C transpose: wave region [64 rows][32 cols] = 4KB; full-line 16B stores
  unsigned short* cst = (w < 4) ? ((w < 2) ? (Ah + w * 2048) : (Al + (w - 2) * 2048))
                                : (Cex + (w - 4) * 2048);
#pragma unroll
  for (int i = 0; i < 4; ++i)
#pragma unroll
    for (int j = 0; j < 2; ++j)
#pragma unroll
      for (int r = 0; r < 4; ++r) {
        int row = i * 16 + q * 4 + r;
        cst[row * 32 + j * 16 + c15] = f2bf(acc[i][j][r]);
      }
  // same-wave LDS write->read (in-order); linear 1KB reads; 64B-line global stores
#pragma unroll
  for (int t2 = 0; t2 < 4; ++t2) {
    int idx = t2 * 64 + lane;
    int row = idx >> 2, ch = idx & 3;
    u16x8 v = *(const u16x8*)&cst[idx * 8];
    int gm = brow + row;
    if (gm < M)
      *(u16x8*)&h1b[(size_t)gm * 256 + w * 32 + ch * 8] = v;
  }
}

// ---------------- GEMM2 fused: h2b = bf16(out1e @ W2) + as2/ad2 epilogue ----------------
__global__ __launch_bounds__(512) void k_gemm2(
    const unsigned short* __restrict__ Ae,
    const unsigned short* __restrict__ Bth, const unsigned short* __restrict__ Btl,
    const float* __restrict__ a_src, const float* __restrict__ a_dst,
    unsigned short* __restrict__ h2b, float* __restrict__ as2, float* __restrict__ ad2,
    int M)
{
  const int t = threadIdx.x, lane = t & 63, w = t >> 6;
  const int lrow = lane & 15, lkb = lane >> 4;
  const int grow = blockIdx.x * 128 + w * 16;

  f32x4 acc[2];
  acc[0] = (f32x4){0.f, 0.f, 0.f, 0.f};
  acc[1] = (f32x4){0.f, 0.f, 0.f, 0.f};

#pragma unroll
  for (int kt = 0; kt < 4; ++kt) {
    const int k0 = kt * 64;
#pragma unroll
    for (int kk = 0; kk < 2; ++kk) {
      bf16x8 a = *(const bf16x8*)&Ae[(size_t)(grow + lrow) * 256 + k0 + kk * 32 + lkb * 8];
#pragma unroll
      for (int j = 0; j < 2; ++j) {
        size_t g = (size_t)(j * 16 + lrow) * 256 + k0 + kk * 32 + lkb * 8;
        bf16x8 bh = *(const bf16x8*)&Bth[g];
        bf16x8 bl = *(const bf16x8*)&Btl[g];
        acc[j] = __builtin_amdgcn_mfma_f32_16x16x32_bf16(a, bh, acc[j], 0, 0, 0);
        acc[j] = __builtin_amdgcn_mfma_f32_16x16x32_bf16(a, bl, acc[j], 0, 0, 0);
      }
    }
  }

  const int c15 = lane & 15, q = lane >> 4;
  float asv[2] = { a_src[c15], a_src[16 + c15] };
  float adv[2] = { a_dst[c15], a_dst[16 + c15] };
#pragma unroll
  for (int r = 0; r < 4; ++r) {
    int gm = grow + q * 4 + r;
    float pS = acc[0][r] * asv[0] + acc[1][r] * asv[1];
    float pD = acc[0][r] * adv[0] + acc[1][r] * adv[1];
#pragma unroll
    for (int off = 1; off < 16; off <<= 1) {
      pS += __shfl_xor(pS, off);
      pD += __shfl_xor(pD, off);
    }
    if (c15 == 0 && gm < M) { as2[gm] = pS; ad2[gm] = pD; }
    if (gm < M) {
      h2b[(size_t)gm * 32 + c15]      = f2bf(acc[0][r]);
      h2b[(size_t)gm * 32 + 16 + c15] = f2bf(acc[1][r]);
    }
  }
}

// ---------------- layer-1 aggregation: wave per node, single pass ----------------
__global__ __launch_bounds__(256) void k_agg1(const unsigned short* __restrict__ h1b,
    const float* __restrict__ as1, const float* __restrict__ ad1,
    const int* __restrict__ rowptr, const int* __restrict__ csrsrc,
    const float* __restrict__ b1, unsigned short* __restrict__ out1e, int n)
{
  __shared__ float alds[4][64][8];
  __shared__ int   slds[4][64];

  int ns = threadIdx.x >> 6;
  int node = blockIdx.x * 4 + ns;
  if (node >= n) return;
  int lane = threadIdx.x & 63;
  int r0 = rowptr[node];
  int deg = rowptr[node + 1] - r0;

  int h = lane & 7;
  int slot = lane >> 3;
  float adv = ad1[node * 8 + h];

  int hh = lane >> 3;
  float s = 0.f;
  float4 acc = make_float4(0.f, 0.f, 0.f, 0.f);

  for (int c0 = 0; c0 < deg; c0 += 64) {
#pragma unroll
    for (int r = 0; r < 8; ++r) {
      int kl = r * 8 + slot;
      int k = c0 + kl;
      if (k < deg) {
        int src = csrsrc[r0 + k];
        float e = fminf(lrelu(as1[src * 8 + h] + adv), 60.f);
        float ex = __expf(e);
        s += ex;
        alds[ns][kl][h] = ex;
        if (h == 0) slds[ns][kl] = src;
      }
    }
    int clen = (deg - c0 < 64) ? (deg - c0) : 64;
#pragma unroll 4
    for (int j = 0; j < clen; ++j) {
      float a = alds[ns][j][hh];
      int src = slds[ns][j];
      ushort4 hv = *(const ushort4*)&h1b[(size_t)src * 256 + lane * 4];
      acc.x = fmaf(a, bf2f(hv.x), acc.x);
      acc.y = fmaf(a, bf2f(hv.y), acc.y);
      acc.z = fmaf(a, bf2f(hv.z), acc.z);
      acc.w = fmaf(a, bf2f(hv.w), acc.w);
    }
  }
#pragma unroll
  for (int off = 8; off < 64; off <<= 1) s += __shfl_xor(s, off);
  float sh = __shfl(s, hh);
  float inv = 1.f / (sh + 1e-16f);

  float4 bv = *(const float4*)&b1[lane * 4];
  float ox = acc.x * inv + bv.x, oy = acc.y * inv + bv.y;
  float oz = acc.z * inv + bv.z, ow = acc.w * inv + bv.w;
  ushort4 ob;
  ob.x = f2bf(ox > 0.f ? ox : expm1f(ox));
  ob.y = f2bf(oy > 0.f ? oy : expm1f(oy));
  ob.z = f2bf(oz > 0.f ? oz : expm1f(oz));
  ob.w = f2bf(ow > 0.f ? ow : expm1f(ow));
  *(ushort4*)&out1e[(size_t)node * 256 + lane * 4] = ob;
}

// ---------------- layer-2 aggregation: 8 lanes/edge, single pass ----------------
__global__ __launch_bounds__(256) void k_agg2(const unsigned short* __restrict__ h2b,
    const float* __restrict__ as2, const float* __restrict__ ad2,
    const int* __restrict__ rowptr, const int* __restrict__ csrsrc,
    const float* __restrict__ b2, float* __restrict__ out, int n)
{
  const int wid = threadIdx.x >> 6;
  const int lane = threadIdx.x & 63;
  const int node = blockIdx.x * 4 + wid;
  if (node >= n) return;

  const int r0 = rowptr[node];
  const int deg = rowptr[node + 1] - r0;
  const float adv = ad2[node];

  const int c4 = lane & 7;
  const int es = lane >> 3;
  float s = 0.f;
  float ax = 0.f, ay = 0.f, az = 0.f, aw = 0.f;

  const int dfull = deg & ~7;
#pragma unroll 2
  for (int c0 = 0; c0 < dfull; c0 += 8) {
    int src = csrsrc[r0 + c0 + es];
    float e = fminf(lrelu(as2[src] + adv), 60.f);
    float ex = __expf(e);
    s += ex;
    ushort4 hv = *(const ushort4*)&h2b[(size_t)src * 32 + c4 * 4];
    ax = fmaf(ex, bf2f(hv.x), ax);
    ay = fmaf(ex, bf2f(hv.y), ay);
    az = fmaf(ex, bf2f(hv.z), az);
    aw = fmaf(ex, bf2f(hv.w), aw);
  }
  if (dfull + es < deg) {
    int src = csrsrc[r0 + dfull + es];
    float e = fminf(lrelu(as2[src] + adv), 60.f);
    float ex = __expf(e);
    s += ex;
    ushort4 hv = *(const ushort4*)&h2b[(size_t)src * 32 + c4 * 4];
    ax = fmaf(ex, bf2f(hv.x), ax);
    ay = fmaf(ex, bf2f(hv.y), ay);
    az = fmaf(ex, bf2f(hv.z), az);
    aw = fmaf(ex, bf2f(hv.w), aw);
  }
#pragma unroll
  for (int off = 8; off < 64; off <<= 1) {
    s  += __shfl_xor(s, off);
    ax += __shfl_xor(ax, off);
    ay += __shfl_xor(ay, off);
    az += __shfl_xor(az, off);
    aw += __shfl_xor(aw, off);
  }
  if (es == 0) {
    float inv = 1.f / (s + 1e-16f);
    float4 o;
    o.x = ax * inv + b2[c4 * 4 + 0];
    o.y = ay * inv + b2[c4 * 4 + 1];
    o.z = az * inv + b2[c4 * 4 + 2];
    o.w = aw * inv + b2[c4 * 4 + 3];
    *(float4*)&out[(size_t)node * 32 + c4 * 4] = o;
  }
}

// ---------------- host launch ----------------
extern "C" void kernel_launch(void* const* d_in, const int* in_sizes, int n_in,
                              void* d_out, int out_size, void* d_ws, size_t ws_size,
                              hipStream_t stream)
{
  const float* x      = (const float*)d_in[0];
  const int*   ei     = (const int*)d_in[1];
  const float* W1     = (const float*)d_in[3];
  const float* a_src1 = (const float*)d_in[4];
  const float* a_dst1 = (const float*)d_in[5];
  const float* b1     = (const float*)d_in[6];
  const float* W2     = (const float*)d_in[7];
  const float* a_src2 = (const float*)d_in[8];
  const float* a_dst2 = (const float*)d_in[9];
  const float* b2     = (const float*)d_in[10];
  float* out = (float*)d_out;

  const int n = in_sizes[0] / 256;            // 50000
  const int E = in_sizes[2];                  // 800000
  const int etot = E + n;                     // 850000
  const int Mpad = ((n + 255) / 256) * 256;   // 50176
  const int NRG = (n + 1023) / 1024;          // 49 node ranges
  const int esl = (etot + 7) / 8;             // edges per slice

  // workspace carve
  unsigned short* h1b   = (unsigned short*)d_ws;           // [n][256] bf16 node-major
  unsigned short* out1e = h1b + (size_t)n * 256;           // [Mpad][256] bf16
  unsigned short* h2b   = out1e + (size_t)Mpad * 256;      // n*32 bf16
  float* as1v = (float*)(h2b + (size_t)n * 32);            // [n][8]
  float* ad1v = as1v + (size_t)n * 8;                      // [n][8]
  float* as2v = ad1v + (size_t)n * 8;                      // n
  float* ad2v = as2v + n;                                  // n
  int* rowptr = (int*)(ad2v + n);                          // n+1
  int* part   = rowptr + (n + 1);                          // NRG*8*1024
  int* csrsrc = part + (size_t)NRG * 8 * 1024;             // etot
  int* bsums  = csrsrc + etot;                             // <=64
  unsigned short* wth  = (unsigned short*)(bsums + 64);    // 65536
  unsigned short* wtl  = wth + 65536;                      // 65536
  unsigned short* w2th = wtl + 65536;                      // 8192
  unsigned short* w2tl = w2th + 8192;                      // 8192

  // prep: weight splits + zero hist partials
  k_prep<<<288, 256, 0, stream>>>(W1, W2, wth, wtl, w2th, w2tl, part, NRG * 8 * 1024);

  // CSR build (atomic-free histogram)
  k_hist<<<NRG * 8, 1024, 0, stream>>>(ei, part, E, etot, esl);

  // h1b/as1/ad1 = gemm1(x, W1) fused
  k_gemm1<<<Mpad / 64, 512, 0, stream>>>(x, wth, wtl, a_src1, a_dst1,
                                         h1b, as1v, ad1v, n);

  k_scan1<<<NRG, 1024, 0, stream>>>(part, rowptr, bsums, n);
  k_scan23<<<(n + 256) / 256, 256, 0, stream>>>(rowptr, bsums, n, etot);
  k_fill<<<NRG * 8, 1024, 0, stream>>>(ei, rowptr, part, csrsrc, E, etot, esl);

  // layer-1 attention (wave per node, all heads, single pass)
  int nb4 = (n + 3) / 4;
  k_agg1<<<nb4, 256, 0, stream>>>(h1b, as1v, ad1v, rowptr, csrsrc, b1, out1e, n);

  // h2b/as2/ad2 = gemm2(out1e, W2) fused
  k_gemm2<<<Mpad / 128, 512, 0, stream>>>(out1e, w2th, w2tl, a_src2, a_dst2,
                                          h2b, as2v, ad2v, n);

  // layer-2 attention -> output
  k_agg2<<<nb4, 256, 0, stream>>>(h2b, as2v, ad2v, rowptr, csrsrc, b2, out, n);
}

// Round 13
// 258.838 us; speedup vs baseline: 1.0184x; 1.0184x over previous
//
#include <hip/hip_runtime.h>
#include <math.h>

typedef __attribute__((ext_vector_type(8))) short bf16x8;
typedef __attribute__((ext_vector_type(8))) unsigned short u16x8;
typedef __attribute__((ext_vector_type(4))) float f32x4;

__device__ __forceinline__ float lrelu(float x) { return x > 0.f ? x : 0.2f * x; }

__device__ __forceinline__ unsigned short f2bf(float f) {
  unsigned int u = __float_as_uint(f);
  unsigned int r = (u + 0x7FFFu + ((u >> 16) & 1u)) >> 16;   // RNE
  return (unsigned short)r;
}
__device__ __forceinline__ float bf2f(unsigned short h) {
  return __uint_as_float(((unsigned int)h) << 16);
}

// swizzled LDS offset (in shorts) for [rows][64]bf16 tile: 16B chunk c16 of row
__device__ __forceinline__ int swz(int row, int c16) {
  return (row * 8 + (c16 ^ (row & 7))) * 8;
}

// ---------------- prep: W1/W2 split+transpose + zero degree/fill counters ----------------
__global__ __launch_bounds__(256) void k_prep(const float* __restrict__ W1,
    const float* __restrict__ W2,
    unsigned short* __restrict__ Wth, unsigned short* __restrict__ Wtl,
    unsigned short* __restrict__ W2th, unsigned short* __restrict__ W2tl,
    int* __restrict__ zeros, int nz)
{
  int bid = blockIdx.x, t = threadIdx.x;
  if (bid < 256) {
    float v = W1[t * 256 + bid];
    unsigned short h = f2bf(v);
    Wth[bid * 256 + t] = h;
    Wtl[bid * 256 + t] = f2bf(v - bf2f(h));
  } else {
    int nn = bid - 256;
    float v = W2[t * 32 + nn];
    unsigned short h = f2bf(v);
    W2th[nn * 256 + t] = h;
    W2tl[nn * 256 + t] = f2bf(v - bf2f(h));
  }
  for (int i = bid * 256 + t; i < nz; i += gridDim.x * 256) zeros[i] = 0;
}

// ---------------- CSR: degree histogram (global atomics; measured ~12us standalone) ----------------
__global__ void k_deg(const int* __restrict__ ei, int* __restrict__ deg, int E, int etot)
{
  int e = blockIdx.x * blockDim.x + threadIdx.x;
  if (e >= etot) return;
  int dst = (e < E) ? ei[E + e] : (e - E);
  atomicAdd(&deg[dst], 1);
}

// ---------------- GEMM1: BM=64, wave-per-head, full-line epilogue stores ----------------
__global__ __launch_bounds__(512, 4) void k_gemm1(
    const float* __restrict__ X,
    const unsigned short* __restrict__ Bth, const unsigned short* __restrict__ Btl,
    const float* __restrict__ a_src, const float* __restrict__ a_dst,
    unsigned short* __restrict__ h1b, float* __restrict__ as1, float* __restrict__ ad1,
    int M)
{
  __shared__ __align__(16) unsigned short Ah[64 * 64];    // 8KB
  __shared__ __align__(16) unsigned short Al[64 * 64];    // 8KB
  __shared__ __align__(16) unsigned short Cex[8 * 1024];  // 16KB (epilogue, waves 4-7)
  const int t = threadIdx.x;
  const int lane = t & 63;
  const int w = t >> 6;               // wave = head
  const int lrow = lane & 15, lkb = lane >> 4;
  const int brow = blockIdx.x * 64;

  f32x4 acc[4][2];
#pragma unroll
  for (int i = 0; i < 4; ++i)
#pragma unroll
    for (int j = 0; j < 2; ++j) acc[i][j] = (f32x4){0.f, 0.f, 0.f, 0.f};

  float4 pref[2];
#pragma unroll
  for (int r = 0; r < 2; ++r) {
    int id = r * 512 + t, m = id >> 4, cq = id & 15, gm = brow + m;
    pref[r] = (gm < M) ? *(const float4*)&X[(size_t)gm * 256 + cq * 4]
                       : make_float4(0.f, 0.f, 0.f, 0.f);
  }

  for (int kt = 0; kt < 4; ++kt) {
    const int k0 = kt * 64;
#pragma unroll
    for (int r = 0; r < 2; ++r) {
      int id = r * 512 + t, m = id >> 4, cq = id & 15;
      float4 v = pref[r];
      unsigned short h0 = f2bf(v.x), h1 = f2bf(v.y), h2 = f2bf(v.z), h3 = f2bf(v.w);
      unsigned short l0 = f2bf(v.x - bf2f(h0)), l1 = f2bf(v.y - bf2f(h1));
      unsigned short l2 = f2bf(v.z - bf2f(h2)), l3 = f2bf(v.w - bf2f(h3));
      int off = swz(m, cq >> 1) + (cq & 1) * 4;
      *(uint2*)&Ah[off] = make_uint2((unsigned)h0 | ((unsigned)h1 << 16),
                                     (unsigned)h2 | ((unsigned)h3 << 16));
      *(uint2*)&Al[off] = make_uint2((unsigned)l0 | ((unsigned)l1 << 16),
                                     (unsigned)l2 | ((unsigned)l3 << 16));
    }
    if (kt < 3) {
#pragma unroll
      for (int r = 0; r < 2; ++r) {
        int id = r * 512 + t, m = id >> 4, cq = id & 15, gm = brow + m;
        pref[r] = (gm < M) ? *(const float4*)&X[(size_t)gm * 256 + k0 + 64 + cq * 4]
                           : make_float4(0.f, 0.f, 0.f, 0.f);
      }
    }
    __syncthreads();
#pragma unroll
    for (int kk = 0; kk < 2; ++kk) {
      bf16x8 bh[2], bl[2];
#pragma unroll
      for (int j = 0; j < 2; ++j) {
        size_t g = (size_t)(w * 32 + j * 16 + lrow) * 256 + k0 + kk * 32 + lkb * 8;
        bh[j] = *(const bf16x8*)&Bth[g];
        bl[j] = *(const bf16x8*)&Btl[g];
      }
#pragma unroll
      for (int i = 0; i < 4; ++i) {
        int row = i * 16 + lrow;
        int lo = swz(row, kk * 4 + lkb);
        bf16x8 ah = *(const bf16x8*)&Ah[lo];
        bf16x8 al = *(const bf16x8*)&Al[lo];
#pragma unroll
        for (int j = 0; j < 2; ++j) {
          acc[i][j] = __builtin_amdgcn_mfma_f32_16x16x32_bf16(ah, bh[j], acc[i][j], 0, 0, 0);
          acc[i][j] = __builtin_amdgcn_mfma_f32_16x16x32_bf16(ah, bl[j], acc[i][j], 0, 0, 0);
          acc[i][j] = __builtin_amdgcn_mfma_f32_16x16x32_bf16(al, bh[j], acc[i][j], 0, 0, 0);
        }
      }
    }
    __syncthreads();
  }

  const int c15 = lane & 15, q = lane >> 4;

  // fused as1/ad1 for head w, interleaved [n][8]
  float asv[2], adv[2];
#pragma unroll
  for (int j = 0; j < 2; ++j) {
    int idx = w * 32 + j * 16 + c15;
    asv[j] = a_src[idx];
    adv[j] = a_dst[idx];
  }
#pragma unroll
  for (int i = 0; i < 4; ++i) {
#pragma unroll
    for (int r = 0; r < 4; ++r) {
      int gm = brow + i * 16 + q * 4 + r;
      float pS = acc[i][0][r] * asv[0] + acc[i][1][r] * asv[1];
      float pD = acc[i][0][r] * adv[0] + acc[i][1][r] * adv[1];
#pragma unroll
      for (int off = 1; off < 16; off <<= 1) {
        pS += __shfl_xor(pS, off);
        pD += __shfl_xor(pD, off);
      }
      if (c15 == 0 && gm < M) {
        as1[(size_t)gm * 8 + w] = pS;
        ad1[(size_t)gm * 8 + w] = pD;
      }
    }
  }

  // one-pass C transpose: wave region [64 rows][32 cols] = 4KB; full-line 16B stores
  unsigned short* cst = (w < 4) ? ((w < 2) ? (Ah + w * 2048) : (Al + (w - 2) * 2048))
                                : (Cex + (w - 4) * 2048);
#pragma unroll
  for (int i = 0; i < 4; ++i)
#pragma unroll
    for (int j = 0; j < 2; ++j)
#pragma unroll
      for (int r = 0; r < 4; ++r) {
        int row = i * 16 + q * 4 + r;
        cst[row * 32 + j * 16 + c15] = f2bf(acc[i][j][r]);
      }
  // same-wave LDS write->read (in-order); linear 1KB reads; 64B-line global stores
#pragma unroll
  for (int t2 = 0; t2 < 4; ++t2) {
    int idx = t2 * 64 + lane;
    int row = idx >> 2, ch = idx & 3;
    u16x8 v = *(const u16x8*)&cst[idx * 8];
    int gm = brow + row;
    if (gm < M)
      *(u16x8*)&h1b[(size_t)gm * 256 + w * 32 + ch * 8] = v;
  }
}

// ---------------- GEMM2 fused: h2b = bf16(out1e @ W2) + as2/ad2 epilogue ----------------
__global__ __launch_bounds__(512) void k_gemm2(
    const unsigned short* __restrict__ Ae,
    const unsigned short* __restrict__ Bth, const unsigned short* __restrict__ Btl,
    const float* __restrict__ a_src, const float* __restrict__ a_dst,
    unsigned short* __restrict__ h2b, float* __restrict__ as2, float* __restrict__ ad2,
    int M)
{
  const int t = threadIdx.x, lane = t & 63, w = t >> 6;
  const int lrow = lane & 15, lkb = lane >> 4;
  const int grow = blockIdx.x * 128 + w * 16;

  f32x4 acc[2];
  acc[0] = (f32x4){0.f, 0.f, 0.f, 0.f};
  acc[1] = (f32x4){0.f, 0.f, 0.f, 0.f};

#pragma unroll
  for (int kt = 0; kt < 4; ++kt) {
    const int k0 = kt * 64;
#pragma unroll
    for (int kk = 0; kk < 2; ++kk) {
      bf16x8 a = *(const bf16x8*)&Ae[(size_t)(grow + lrow) * 256 + k0 + kk * 32 + lkb * 8];
#pragma unroll
      for (int j = 0; j < 2; ++j) {
        size_t g = (size_t)(j * 16 + lrow) * 256 + k0 + kk * 32 + lkb * 8;
        bf16x8 bh = *(const bf16x8*)&Bth[g];
        bf16x8 bl = *(const bf16x8*)&Btl[g];
        acc[j] = __builtin_amdgcn_mfma_f32_16x16x32_bf16(a, bh, acc[j], 0, 0, 0);
        acc[j] = __builtin_amdgcn_mfma_f32_16x16x32_bf16(a, bl, acc[j], 0, 0, 0);
      }
    }
  }

  const int c15 = lane & 15, q = lane >> 4;
  float asv[2] = { a_src[c15], a_src[16 + c15] };
  float adv[2] = { a_dst[c15], a_dst[16 + c15] };
#pragma unroll
  for (int r = 0; r < 4; ++r) {
    int gm = grow + q * 4 + r;
    float pS = acc[0][r] * asv[0] + acc[1][r] * asv[1];
    float pD = acc[0][r] * adv[0] + acc[1][r] * adv[1];
#pragma unroll
    for (int off = 1; off < 16; off <<= 1) {
      pS += __shfl_xor(pS, off);
      pD += __shfl_xor(pD, off);
    }
    if (c15 == 0 && gm < M) { as2[gm] = pS; ad2[gm] = pD; }
    if (gm < M) {
      h2b[(size_t)gm * 32 + c15]      = f2bf(acc[0][r]);
      h2b[(size_t)gm * 32 + 16 + c15] = f2bf(acc[1][r]);
    }
  }
}

// ---------------- CSR scans ----------------
__global__ void k_scan1(const int* __restrict__ deg, int* __restrict__ rowptr,
                        int* __restrict__ bsums, int n)
{
  __shared__ int sm[2][1024];
  int t = threadIdx.x, b = blockIdx.x;
  int i = b * 1024 + t;
  int v = (i < n) ? deg[i] : 0;
  sm[0][t] = v;
  __syncthreads();
  int pb = 0;
  for (int off = 1; off < 1024; off <<= 1) {
    int x = sm[pb][t];
    if (t >= off) x += sm[pb][t - off];
    sm[pb ^ 1][t] = x;
    pb ^= 1;
    __syncthreads();
  }
  if (i < n) rowptr[i] = sm[pb][t] - v;
  if (t == 1023) bsums[b] = sm[pb][1023];
}

__global__ void k_scan23(int* __restrict__ rowptr, const int* __restrict__ bsums,
                         int n, int etot)
{
  int i = blockIdx.x * blockDim.x + threadIdx.x;
  if (i > n) return;
  int b = i >> 10;
  int pre = 0;
  for (int k = 0; k < b; ++k) pre += bsums[k];
  if (i < n) rowptr[i] += pre;
  if (i == 0) rowptr[n] = etot;
}

__global__ void k_fill(const int* __restrict__ ei, const int* __restrict__ rowptr,
                       int* __restrict__ fillc, int* __restrict__ csrsrc, int E, int etot)
{
  int e = blockIdx.x * blockDim.x + threadIdx.x;
  if (e >= etot) return;
  int src, dst;
  if (e < E) { src = ei[e]; dst = ei[E + e]; }
  else { src = dst = e - E; }
  int pos = rowptr[dst] + atomicAdd(&fillc[dst], 1);
  csrsrc[pos] = src;
}

// ---------------- layer-1 aggregation: wave per node, single pass ----------------
__global__ __launch_bounds__(256) void k_agg1(const unsigned short* __restrict__ h1b,
    const float* __restrict__ as1, const float* __restrict__ ad1,
    const int* __restrict__ rowptr, const int* __restrict__ csrsrc,
    const float* __restrict__ b1, unsigned short* __restrict__ out1e, int n)
{
  __shared__ float alds[4][64][8];
  __shared__ int   slds[4][64];

  int ns = threadIdx.x >> 6;
  int node = blockIdx.x * 4 + ns;
  if (node >= n) return;
  int lane = threadIdx.x & 63;
  int r0 = rowptr[node];
  int deg = rowptr[node + 1] - r0;

  int h = lane & 7;
  int slot = lane >> 3;
  float adv = ad1[node * 8 + h];

  int hh = lane >> 3;
  float s = 0.f;
  float4 acc = make_float4(0.f, 0.f, 0.f, 0.f);

  for (int c0 = 0; c0 < deg; c0 += 64) {
#pragma unroll
    for (int r = 0; r < 8; ++r) {
      int kl = r * 8 + slot;
      int k = c0 + kl;
      if (k < deg) {
        int src = csrsrc[r0 + k];
        float e = fminf(lrelu(as1[src * 8 + h] + adv), 60.f);
        float ex = __expf(e);
        s += ex;
        alds[ns][kl][h] = ex;
        if (h == 0) slds[ns][kl] = src;
      }
    }
    int clen = (deg - c0 < 64) ? (deg - c0) : 64;
#pragma unroll 4
    for (int j = 0; j < clen; ++j) {
      float a = alds[ns][j][hh];
      int src = slds[ns][j];
      ushort4 hv = *(const ushort4*)&h1b[(size_t)src * 256 + lane * 4];
      acc.x = fmaf(a, bf2f(hv.x), acc.x);
      acc.y = fmaf(a, bf2f(hv.y), acc.y);
      acc.z = fmaf(a, bf2f(hv.z), acc.z);
      acc.w = fmaf(a, bf2f(hv.w), acc.w);
    }
  }
#pragma unroll
  for (int off = 8; off < 64; off <<= 1) s += __shfl_xor(s, off);
  float sh = __shfl(s, hh);
  float inv = 1.f / (sh + 1e-16f);

  float4 bv = *(const float4*)&b1[lane * 4];
  float ox = acc.x * inv + bv.x, oy = acc.y * inv + bv.y;
  float oz = acc.z * inv + bv.z, ow = acc.w * inv + bv.w;
  ushort4 ob;
  ob.x = f2bf(ox > 0.f ? ox : expm1f(ox));
  ob.y = f2bf(oy > 0.f ? oy : expm1f(oy));
  ob.z = f2bf(oz > 0.f ? oz : expm1f(oz));
  ob.w = f2bf(ow > 0.f ? ow : expm1f(ow));
  *(ushort4*)&out1e[(size_t)node * 256 + lane * 4] = ob;
}

// ---------------- layer-2 aggregation: 8 lanes/edge, single pass ----------------
__global__ __launch_bounds__(256) void k_agg2(const unsigned short* __restrict__ h2b,
    const float* __restrict__ as2, const float* __restrict__ ad2,
    const int* __restrict__ rowptr, const int* __restrict__ csrsrc,
    const float* __restrict__ b2, float* __restrict__ out, int n)
{
  const int wid = threadIdx.x >> 6;
  const int lane = threadIdx.x & 63;
  const int node = blockIdx.x * 4 + wid;
  if (node >= n) return;

  const int r0 = rowptr[node];
  const int deg = rowptr[node + 1] - r0;
  const float adv = ad2[node];

  const int c4 = lane & 7;
  const int es = lane >> 3;
  float s = 0.f;
  float ax = 0.f, ay = 0.f, az = 0.f, aw = 0.f;

  const int dfull = deg & ~7;
#pragma unroll 2
  for (int c0 = 0; c0 < dfull; c0 += 8) {
    int src = csrsrc[r0 + c0 + es];
    float e = fminf(lrelu(as2[src] + adv), 60.f);
    float ex = __expf(e);
    s += ex;
    ushort4 hv = *(const ushort4*)&h2b[(size_t)src * 32 + c4 * 4];
    ax = fmaf(ex, bf2f(hv.x), ax);
    ay = fmaf(ex, bf2f(hv.y), ay);
    az = fmaf(ex, bf2f(hv.z), az);
    aw = fmaf(ex, bf2f(hv.w), aw);
  }
  if (dfull + es < deg) {
    int src = csrsrc[r0 + dfull + es];
    float e = fminf(lrelu(as2[src] + adv), 60.f);
    float ex = __expf(e);
    s += ex;
    ushort4 hv = *(const ushort4*)&h2b[(size_t)src * 32 + c4 * 4];
    ax = fmaf(ex, bf2f(hv.x), ax);
    ay = fmaf(ex, bf2f(hv.y), ay);
    az = fmaf(ex, bf2f(hv.z), az);
    aw = fmaf(ex, bf2f(hv.w), aw);
  }
#pragma unroll
  for (int off = 8; off < 64; off <<= 1) {
    s  += __shfl_xor(s, off);
    ax += __shfl_xor(ax, off);
    ay += __shfl_xor(ay, off);
    az += __shfl_xor(az, off);
    aw += __shfl_xor(aw, off);
  }
  if (es == 0) {
    float inv = 1.f / (s + 1e-16f);
    float4 o;
    o.x = ax * inv + b2[c4 * 4 + 0];
    o.y = ay * inv + b2[c4 * 4 + 1];
    o.z = az * inv + b2[c4 * 4 + 2];
    o.w = aw * inv + b2[c4 * 4 + 3];
    *(float4*)&out[(size_t)node * 32 + c4 * 4] = o;
  }
}

// ---------------- host launch ----------------
extern "C" void kernel_launch(void* const* d_in, const int* in_sizes, int n_in,
                              void* d_out, int out_size, void* d_ws, size_t ws_size,
                              hipStream_t stream)
{
  const float* x      = (const float*)d_in[0];
  const int*   ei     = (const int*)d_in[1];
  const float* W1     = (const float*)d_in[3];
  const float* a_src1 = (const float*)d_in[4];
  const float* a_dst1 = (const float*)d_in[5];
  const float* b1     = (const float*)d_in[6];
  const float* W2     = (const float*)d_in[7];
  const float* a_src2 = (const float*)d_in[8];
  const float* a_dst2 = (const float*)d_in[9];
  const float* b2     = (const float*)d_in[10];
  float* out = (float*)d_out;

  const int n = in_sizes[0] / 256;            // 50000
  const int E = in_sizes[2];                  // 800000
  const int etot = E + n;                     // 850000
  const int Mpad = ((n + 255) / 256) * 256;   // 50176

  // workspace carve
  unsigned short* h1b   = (unsigned short*)d_ws;           // [n][256] bf16 node-major
  unsigned short* out1e = h1b + (size_t)n * 256;           // [Mpad][256] bf16
  unsigned short* h2b   = out1e + (size_t)Mpad * 256;      // n*32 bf16
  float* as1v = (float*)(h2b + (size_t)n * 32);            // [n][8]
  float* ad1v = as1v + (size_t)n * 8;                      // [n][8]
  float* as2v = ad1v + (size_t)n * 8;                      // n
  float* ad2v = as2v + n;                                  // n
  int* rowptr = (int*)(ad2v + n);                          // n+1
  int* degc   = rowptr + (n + 1);                          // n
  int* fillc  = degc + n;                                  // n
  int* csrsrc = fillc + n;                                 // etot
  int* bsums  = csrsrc + etot;                             // <=64
  unsigned short* wth  = (unsigned short*)(bsums + 64);    // 65536
  unsigned short* wtl  = wth + 65536;                      // 65536
  unsigned short* w2th = wtl + 65536;                      // 8192
  unsigned short* w2tl = w2th + 8192;                      // 8192

  // prep: weight splits + zero degc/fillc (2n ints)
  k_prep<<<288, 256, 0, stream>>>(W1, W2, wth, wtl, w2th, w2tl, degc, 2 * n);

  // degree histogram (global atomics)
  int eb = (etot + 255) / 256;
  k_deg<<<eb, 256, 0, stream>>>(ei, degc, E, etot);

  // h1b/as1/ad1 = gemm1(x, W1) fused
  k_gemm1<<<Mpad / 64, 512, 0, stream>>>(x, wth, wtl, a_src1, a_dst1,
                                         h1b, as1v, ad1v, n);

  // CSR scans + fill
  int nblk = (n + 1023) / 1024;
  k_scan1<<<nblk, 1024, 0, stream>>>(degc, rowptr, bsums, n);
  k_scan23<<<(n + 256) / 256, 256, 0, stream>>>(rowptr, bsums, n, etot);
  k_fill<<<eb, 256, 0, stream>>>(ei, rowptr, fillc, csrsrc, E, etot);

  // layer-1 attention (wave per node, all heads, single pass)
  int nb4 = (n + 3) / 4;
  k_agg1<<<nb4, 256, 0, stream>>>(h1b, as1v, ad1v, rowptr, csrsrc, b1, out1e, n);

  // h2b/as2/ad2 = gemm2(out1e, W2) fused
  k_gemm2<<<Mpad / 128, 512, 0, stream>>>(out1e, w2th, w2tl, a_src2, a_dst2,
                                          h2b, as2v, ad2v, n);

  // layer-2 attention -> output
  k_agg2<<<nb4, 256, 0, stream>>>(h2b, as2v, ad2v, rowptr, csrsrc, b2, out, n);
}

// Round 14
// 212.333 us; speedup vs baseline: 1.2415x; 1.2190x over previous
//
#include <hip/hip_runtime.h>
#include <math.h>

typedef __attribute__((ext_vector_type(8))) short bf16x8;
typedef __attribute__((ext_vector_type(8))) unsigned short u16x8;
typedef __attribute__((ext_vector_type(4))) float f32x4;

__device__ __forceinline__ float lrelu(float x) { return x > 0.f ? x : 0.2f * x; }

__device__ __forceinline__ unsigned short f2bf(float f) {
  unsigned int u = __float_as_uint(f);
  unsigned int r = (u + 0x7FFFu + ((u >> 16) & 1u)) >> 16;   // RNE
  return (unsigned short)r;
}
__device__ __forceinline__ float bf2f(unsigned short h) {
  return __uint_as_float(((unsigned int)h) << 16);
}

// swizzled LDS offset (in shorts) for [rows][64]bf16 tile: 16B chunk c16 of row
__device__ __forceinline__ int swz(int row, int c16) {
  return (row * 8 + (c16 ^ (row & 7))) * 8;
}

// ---------------- prep: W1/W2 split+transpose + zero degree/fill counters ----------------
__global__ __launch_bounds__(256) void k_prep(const float* __restrict__ W1,
    const float* __restrict__ W2,
    unsigned short* __restrict__ Wth, unsigned short* __restrict__ Wtl,
    unsigned short* __restrict__ W2th, unsigned short* __restrict__ W2tl,
    int* __restrict__ zeros, int nz)
{
  int bid = blockIdx.x, t = threadIdx.x;
  if (bid < 256) {
    float v = W1[t * 256 + bid];
    unsigned short h = f2bf(v);
    Wth[bid * 256 + t] = h;
    Wtl[bid * 256 + t] = f2bf(v - bf2f(h));
  } else {
    int nn = bid - 256;
    float v = W2[t * 32 + nn];
    unsigned short h = f2bf(v);
    W2th[nn * 256 + t] = h;
    W2tl[nn * 256 + t] = f2bf(v - bf2f(h));
  }
  for (int i = bid * 256 + t; i < nz; i += gridDim.x * 256) zeros[i] = 0;
}

// ---------------- GEMM1 mega-kernel: gemm blocks [0,ntiles) + CSR blocks [ntiles,grid) ----------------
// csr_mode 0: degree histogram into cnt. csr_mode 1: CSR fill (cnt=fillc, needs rowptr).
__global__ __launch_bounds__(512, 4) void k_gemm1(
    const float* __restrict__ X,
    const unsigned short* __restrict__ Bth, const unsigned short* __restrict__ Btl,
    const float* __restrict__ a_src, const float* __restrict__ a_dst,
    unsigned short* __restrict__ h1b, float* __restrict__ as1, float* __restrict__ ad1,
    int M, int tile0, int ntiles, int csr_mode,
    const int* __restrict__ ei, int* __restrict__ cnt,
    const int* __restrict__ rowptr, int* __restrict__ csrsrc, int E, int etot)
{
  __shared__ __align__(16) unsigned short Ah[64 * 64];    // 8KB
  __shared__ __align__(16) unsigned short Al[64 * 64];    // 8KB
  __shared__ __align__(16) unsigned short Cex[8 * 1024];  // 16KB (epilogue, waves 4-7)
  const int t = threadIdx.x;

  // CSR helper blocks: fill free CU slots, run concurrently with GEMM blocks
  if (blockIdx.x >= ntiles) {
    int b = blockIdx.x - ntiles;
    int stride = (gridDim.x - ntiles) * 512;
    if (csr_mode == 0) {
      for (int e = b * 512 + t; e < etot; e += stride) {
        int dst = (e < E) ? ei[E + e] : (e - E);
        atomicAdd(&cnt[dst], 1);
      }
    } else {
      for (int e = b * 512 + t; e < etot; e += stride) {
        int src, dst;
        if (e < E) { src = ei[e]; dst = ei[E + e]; }
        else { src = dst = e - E; }
        int pos = rowptr[dst] + atomicAdd(&cnt[dst], 1);
        csrsrc[pos] = src;
      }
    }
    return;
  }

  const int lane = t & 63;
  const int w = t >> 6;               // wave = head
  const int lrow = lane & 15, lkb = lane >> 4;
  const int brow = (tile0 + blockIdx.x) * 64;

  f32x4 acc[4][2];
#pragma unroll
  for (int i = 0; i < 4; ++i)
#pragma unroll
    for (int j = 0; j < 2; ++j) acc[i][j] = (f32x4){0.f, 0.f, 0.f, 0.f};

  float4 pref[2];
#pragma unroll
  for (int r = 0; r < 2; ++r) {
    int id = r * 512 + t, m = id >> 4, cq = id & 15, gm = brow + m;
    pref[r] = (gm < M) ? *(const float4*)&X[(size_t)gm * 256 + cq * 4]
                       : make_float4(0.f, 0.f, 0.f, 0.f);
  }

  for (int kt = 0; kt < 4; ++kt) {
    const int k0 = kt * 64;
#pragma unroll
    for (int r = 0; r < 2; ++r) {
      int id = r * 512 + t, m = id >> 4, cq = id & 15;
      float4 v = pref[r];
      unsigned short h0 = f2bf(v.x), h1 = f2bf(v.y), h2 = f2bf(v.z), h3 = f2bf(v.w);
      unsigned short l0 = f2bf(v.x - bf2f(h0)), l1 = f2bf(v.y - bf2f(h1));
      unsigned short l2 = f2bf(v.z - bf2f(h2)), l3 = f2bf(v.w - bf2f(h3));
      int off = swz(m, cq >> 1) + (cq & 1) * 4;
      *(uint2*)&Ah[off] = make_uint2((unsigned)h0 | ((unsigned)h1 << 16),
                                     (unsigned)h2 | ((unsigned)h3 << 16));
      *(uint2*)&Al[off] = make_uint2((unsigned)l0 | ((unsigned)l1 << 16),
                                     (unsigned)l2 | ((unsigned)l3 << 16));
    }
    if (kt < 3) {
#pragma unroll
      for (int r = 0; r < 2; ++r) {
        int id = r * 512 + t, m = id >> 4, cq = id & 15, gm = brow + m;
        pref[r] = (gm < M) ? *(const float4*)&X[(size_t)gm * 256 + k0 + 64 + cq * 4]
                           : make_float4(0.f, 0.f, 0.f, 0.f);
      }
    }
    __syncthreads();
#pragma unroll
    for (int kk = 0; kk < 2; ++kk) {
      bf16x8 bh[2], bl[2];
#pragma unroll
      for (int j = 0; j < 2; ++j) {
        size_t g = (size_t)(w * 32 + j * 16 + lrow) * 256 + k0 + kk * 32 + lkb * 8;
        bh[j] = *(const bf16x8*)&Bth[g];
        bl[j] = *(const bf16x8*)&Btl[g];
      }
#pragma unroll
      for (int i = 0; i < 4; ++i) {
        int row = i * 16 + lrow;
        int lo = swz(row, kk * 4 + lkb);
        bf16x8 ah = *(const bf16x8*)&Ah[lo];
        bf16x8 al = *(const bf16x8*)&Al[lo];
#pragma unroll
        for (int j = 0; j < 2; ++j) {
          acc[i][j] = __builtin_amdgcn_mfma_f32_16x16x32_bf16(ah, bh[j], acc[i][j], 0, 0, 0);
          acc[i][j] = __builtin_amdgcn_mfma_f32_16x16x32_bf16(ah, bl[j], acc[i][j], 0, 0, 0);
          acc[i][j] = __builtin_amdgcn_mfma_f32_16x16x32_bf16(al, bh[j], acc[i][j], 0, 0, 0);
        }
      }
    }
    __syncthreads();
  }

  const int c15 = lane & 15, q = lane >> 4;

  // fused as1/ad1 for head w, interleaved [n][8]
  float asv[2], adv[2];
#pragma unroll
  for (int j = 0; j < 2; ++j) {
    int idx = w * 32 + j * 16 + c15;
    asv[j] = a_src[idx];
    adv[j] = a_dst[idx];
  }
#pragma unroll
  for (int i = 0; i < 4; ++i) {
#pragma unroll
    for (int r = 0; r < 4; ++r) {
      int gm = brow + i * 16 + q * 4 + r;
      float pS = acc[i][0][r] * asv[0] + acc[i][1][r] * asv[1];
      float pD = acc[i][0][r] * adv[0] + acc[i][1][r] * adv[1];
#pragma unroll
      for (int off = 1; off < 16; off <<= 1) {
        pS += __shfl_xor(pS, off);
        pD += __shfl_xor(pD, off);
      }
      if (c15 == 0 && gm < M) {
        as1[(size_t)gm * 8 + w] = pS;
        ad1[(size_t)gm * 8 + w] = pD;
      }
    }
  }

  // one-pass C transpose: wave region [64 rows][32 cols] = 4KB; full-line 16B stores
  unsigned short* cst = (w < 4) ? ((w < 2) ? (Ah + w * 2048) : (Al + (w - 2) * 2048))
                                : (Cex + (w - 4) * 2048);
#pragma unroll
  for (int i = 0; i < 4; ++i)
#pragma unroll
    for (int j = 0; j < 2; ++j)
#pragma unroll
      for (int r = 0; r < 4; ++r) {
        int row = i * 16 + q * 4 + r;
        cst[row * 32 + j * 16 + c15] = f2bf(acc[i][j][r]);
      }
#pragma unroll
  for (int t2 = 0; t2 < 4; ++t2) {
    int idx = t2 * 64 + lane;
    int row = idx >> 2, ch = idx & 3;
    u16x8 v = *(const u16x8*)&cst[idx * 8];
    int gm = brow + row;
    if (gm < M)
      *(u16x8*)&h1b[(size_t)gm * 256 + w * 32 + ch * 8] = v;
  }
}

// ---------------- GEMM2 fused: h2b = bf16(out1e @ W2) + as2/ad2 epilogue ----------------
__global__ __launch_bounds__(512) void k_gemm2(
    const unsigned short* __restrict__ Ae,
    const unsigned short* __restrict__ Bth, const unsigned short* __restrict__ Btl,
    const float* __restrict__ a_src, const float* __restrict__ a_dst,
    unsigned short* __restrict__ h2b, float* __restrict__ as2, float* __restrict__ ad2,
    int M)
{
  const int t = threadIdx.x, lane = t & 63, w = t >> 6;
  const int lrow = lane & 15, lkb = lane >> 4;
  const int grow = blockIdx.x * 128 + w * 16;

  f32x4 acc[2];
  acc[0] = (f32x4){0.f, 0.f, 0.f, 0.f};
  acc[1] = (f32x4){0.f, 0.f, 0.f, 0.f};

#pragma unroll
  for (int kt = 0; kt < 4; ++kt) {
    const int k0 = kt * 64;
#pragma unroll
    for (int kk = 0; kk < 2; ++kk) {
      bf16x8 a = *(const bf16x8*)&Ae[(size_t)(grow + lrow) * 256 + k0 + kk * 32 + lkb * 8];
#pragma unroll
      for (int j = 0; j < 2; ++j) {
        size_t g = (size_t)(j * 16 + lrow) * 256 + k0 + kk * 32 + lkb * 8;
        bf16x8 bh = *(const bf16x8*)&Bth[g];
        bf16x8 bl = *(const bf16x8*)&Btl[g];
        acc[j] = __builtin_amdgcn_mfma_f32_16x16x32_bf16(a, bh, acc[j], 0, 0, 0);
        acc[j] = __builtin_amdgcn_mfma_f32_16x16x32_bf16(a, bl, acc[j], 0, 0, 0);
      }
    }
  }

  const int c15 = lane & 15, q = lane >> 4;
  float asv[2] = { a_src[c15], a_src[16 + c15] };
  float adv[2] = { a_dst[c15], a_dst[16 + c15] };
#pragma unroll
  for (int r = 0; r < 4; ++r) {
    int gm = grow + q * 4 + r;
    float pS = acc[0][r] * asv[0] + acc[1][r] * asv[1];
    float pD = acc[0][r] * adv[0] + acc[1][r] * adv[1];
#pragma unroll
    for (int off = 1; off < 16; off <<= 1) {
      pS += __shfl_xor(pS, off);
      pD += __shfl_xor(pD, off);
    }
    if (c15 == 0 && gm < M) { as2[gm] = pS; ad2[gm] = pD; }
    if (gm < M) {
      h2b[(size_t)gm * 32 + c15]      = f2bf(acc[0][r]);
      h2b[(size_t)gm * 32 + 16 + c15] = f2bf(acc[1][r]);
    }
  }
}

// ---------------- CSR scans ----------------
__global__ void k_scan1(const int* __restrict__ deg, int* __restrict__ rowptr,
                        int* __restrict__ bsums, int n)
{
  __shared__ int sm[2][1024];
  int t = threadIdx.x, b = blockIdx.x;
  int i = b * 1024 + t;
  int v = (i < n) ? deg[i] : 0;
  sm[0][t] = v;
  __syncthreads();
  int pb = 0;
  for (int off = 1; off < 1024; off <<= 1) {
    int x = sm[pb][t];
    if (t >= off) x += sm[pb][t - off];
    sm[pb ^ 1][t] = x;
    pb ^= 1;
    __syncthreads();
  }
  if (i < n) rowptr[i] = sm[pb][t] - v;
  if (t == 1023) bsums[b] = sm[pb][1023];
}

__global__ void k_scan23(int* __restrict__ rowptr, const int* __restrict__ bsums,
                         int n, int etot)
{
  int i = blockIdx.x * blockDim.x + threadIdx.x;
  if (i > n) return;
  int b = i >> 10;
  int pre = 0;
  for (int k = 0; k < b; ++k) pre += bsums[k];
  if (i < n) rowptr[i] += pre;
  if (i == 0) rowptr[n] = etot;
}

// ---------------- layer-1 aggregation: wave per node, single pass ----------------
__global__ __launch_bounds__(256) void k_agg1(const unsigned short* __restrict__ h1b,
    const float* __restrict__ as1, const float* __restrict__ ad1,
    const int* __restrict__ rowptr, const int* __restrict__ csrsrc,
    const float* __restrict__ b1, unsigned short* __restrict__ out1e, int n)
{
  __shared__ float alds[4][64][8];
  __shared__ int   slds[4][64];

  int ns = threadIdx.x >> 6;
  int node = blockIdx.x * 4 + ns;
  if (node >= n) return;
  int lane = threadIdx.x & 63;
  int r0 = rowptr[node];
  int deg = rowptr[node + 1] - r0;

  int h = lane & 7;
  int slot = lane >> 3;
  float adv = ad1[node * 8 + h];

  int hh = lane >> 3;
  float s = 0.f;
  float4 acc = make_float4(0.f, 0.f, 0.f, 0.f);

  for (int c0 = 0; c0 < deg; c0 += 64) {
#pragma unroll
    for (int r = 0; r < 8; ++r) {
      int kl = r * 8 + slot;
      int k = c0 + kl;
      if (k < deg) {
        int src = csrsrc[r0 + k];
        float e = fminf(lrelu(as1[src * 8 + h] + adv), 60.f);
        float ex = __expf(e);
        s += ex;
        alds[ns][kl][h] = ex;
        if (h == 0) slds[ns][kl] = src;
      }
    }
    int clen = (deg - c0 < 64) ? (deg - c0) : 64;
#pragma unroll 4
    for (int j = 0; j < clen; ++j) {
      float a = alds[ns][j][hh];
      int src = slds[ns][j];
      ushort4 hv = *(const ushort4*)&h1b[(size_t)src * 256 + lane * 4];
      acc.x = fmaf(a, bf2f(hv.x), acc.x);
      acc.y = fmaf(a, bf2f(hv.y), acc.y);
      acc.z = fmaf(a, bf2f(hv.z), acc.z);
      acc.w = fmaf(a, bf2f(hv.w), acc.w);
    }
  }
#pragma unroll
  for (int off = 8; off < 64; off <<= 1) s += __shfl_xor(s, off);
  float sh = __shfl(s, hh);
  float inv = 1.f / (sh + 1e-16f);

  float4 bv = *(const float4*)&b1[lane * 4];
  float ox = acc.x * inv + bv.x, oy = acc.y * inv + bv.y;
  float oz = acc.z * inv + bv.z, ow = acc.w * inv + bv.w;
  ushort4 ob;
  ob.x = f2bf(ox > 0.f ? ox : expm1f(ox));
  ob.y = f2bf(oy > 0.f ? oy : expm1f(oy));
  ob.z = f2bf(oz > 0.f ? oz : expm1f(oz));
  ob.w = f2bf(ow > 0.f ? ow : expm1f(ow));
  *(ushort4*)&out1e[(size_t)node * 256 + lane * 4] = ob;
}

// ---------------- layer-2 aggregation: 8 lanes/edge, single pass ----------------
__global__ __launch_bounds__(256) void k_agg2(const unsigned short* __restrict__ h2b,
    const float* __restrict__ as2, const float* __restrict__ ad2,
    const int* __restrict__ rowptr, const int* __restrict__ csrsrc,
    const float* __restrict__ b2, float* __restrict__ out, int n)
{
  const int wid = threadIdx.x >> 6;
  const int lane = threadIdx.x & 63;
  const int node = blockIdx.x * 4 + wid;
  if (node >= n) return;

  const int r0 = rowptr[node];
  const int deg = rowptr[node + 1] - r0;
  const float adv = ad2[node];

  const int c4 = lane & 7;
  const int es = lane >> 3;
  float s = 0.f;
  float ax = 0.f, ay = 0.f, az = 0.f, aw = 0.f;

  const int dfull = deg & ~7;
#pragma unroll 2
  for (int c0 = 0; c0 < dfull; c0 += 8) {
    int src = csrsrc[r0 + c0 + es];
    float e = fminf(lrelu(as2[src] + adv), 60.f);
    float ex = __expf(e);
    s += ex;
    ushort4 hv = *(const ushort4*)&h2b[(size_t)src * 32 + c4 * 4];
    ax = fmaf(ex, bf2f(hv.x), ax);
    ay = fmaf(ex, bf2f(hv.y), ay);
    az = fmaf(ex, bf2f(hv.z), az);
    aw = fmaf(ex, bf2f(hv.w), aw);
  }
  if (dfull + es < deg) {
    int src = csrsrc[r0 + dfull + es];
    float e = fminf(lrelu(as2[src] + adv), 60.f);
    float ex = __expf(e);
    s += ex;
    ushort4 hv = *(const ushort4*)&h2b[(size_t)src * 32 + c4 * 4];
    ax = fmaf(ex, bf2f(hv.x), ax);
    ay = fmaf(ex, bf2f(hv.y), ay);
    az = fmaf(ex, bf2f(hv.z), az);
    aw = fmaf(ex, bf2f(hv.w), aw);
  }
#pragma unroll
  for (int off = 8; off < 64; off <<= 1) {
    s  += __shfl_xor(s, off);
    ax += __shfl_xor(ax, off);
    ay += __shfl_xor(ay, off);
    az += __shfl_xor(az, off);
    aw += __shfl_xor(aw, off);
  }
  if (es == 0) {
    float inv = 1.f / (s + 1e-16f);
    float4 o;
    o.x = ax * inv + b2[c4 * 4 + 0];
    o.y = ay * inv + b2[c4 * 4 + 1];
    o.z = az * inv + b2[c4 * 4 + 2];
    o.w = aw * inv + b2[c4 * 4 + 3];
    *(float4*)&out[(size_t)node * 32 + c4 * 4] = o;
  }
}

// ---------------- host launch ----------------
extern "C" void kernel_launch(void* const* d_in, const int* in_sizes, int n_in,
                              void* d_out, int out_size, void* d_ws, size_t ws_size,
                              hipStream_t stream)
{
  const float* x      = (const float*)d_in[0];
  const int*   ei     = (const int*)d_in[1];
  const float* W1     = (const float*)d_in[3];
  const float* a_src1 = (const float*)d_in[4];
  const float* a_dst1 = (const float*)d_in[5];
  const float* b1     = (const float*)d_in[6];
  const float* W2     = (const float*)d_in[7];
  const float* a_src2 = (const float*)d_in[8];
  const float* a_dst2 = (const float*)d_in[9];
  const float* b2     = (const float*)d_in[10];
  float* out = (float*)d_out;

  const int n = in_sizes[0] / 256;            // 50000
  const int E = in_sizes[2];                  // 800000
  const int etot = E + n;                     // 850000
  const int Mpad = ((n + 255) / 256) * 256;   // 50176
  const int NT = Mpad / 64;                   // 784 gemm1 tiles
  const int HT = NT / 2;                      // 392 per half
  const int CB = 256;                         // CSR helper blocks per half

  // workspace carve
  unsigned short* h1b   = (unsigned short*)d_ws;           // [n][256] bf16 node-major
  unsigned short* out1e = h1b + (size_t)n * 256;           // [Mpad][256] bf16
  unsigned short* h2b   = out1e + (size_t)Mpad * 256;      // n*32 bf16
  float* as1v = (float*)(h2b + (size_t)n * 32);            // [n][8]
  float* ad1v = as1v + (size_t)n * 8;                      // [n][8]
  float* as2v = ad1v + (size_t)n * 8;                      // n
  float* ad2v = as2v + n;                                  // n
  int* rowptr = (int*)(ad2v + n);                          // n+1
  int* degc   = rowptr + (n + 1);                          // n
  int* fillc  = degc + n;                                  // n
  int* csrsrc = fillc + n;                                 // etot
  int* bsums  = csrsrc + etot;                             // <=64
  unsigned short* wth  = (unsigned short*)(bsums + 64);    // 65536
  unsigned short* wtl  = wth + 65536;                      // 65536
  unsigned short* w2th = wtl + 65536;                      // 8192
  unsigned short* w2tl = w2th + 8192;                      // 8192

  // prep: weight splits + zero degc/fillc (2n ints)
  k_prep<<<288, 256, 0, stream>>>(W1, W2, wth, wtl, w2th, w2tl, degc, 2 * n);

  // half 1: gemm1 rows [0, HT*64) || degree histogram
  k_gemm1<<<HT + CB, 512, 0, stream>>>(x, wth, wtl, a_src1, a_dst1,
                                       h1b, as1v, ad1v, n, 0, HT, 0,
                                       ei, degc, nullptr, csrsrc, E, etot);

  // CSR scans
  int nblk = (n + 1023) / 1024;
  k_scan1<<<nblk, 1024, 0, stream>>>(degc, rowptr, bsums, n);
  k_scan23<<<(n + 256) / 256, 256, 0, stream>>>(rowptr, bsums, n, etot);

  // half 2: gemm1 rows [HT*64, Mpad) || CSR fill
  k_gemm1<<<HT + CB, 512, 0, stream>>>(x, wth, wtl, a_src1, a_dst1,
                                       h1b, as1v, ad1v, n, HT, HT, 1,
                                       ei, fillc, rowptr, csrsrc, E, etot);

  // layer-1 attention (wave per node, all heads, single pass)
  int nb4 = (n + 3) / 4;
  k_agg1<<<nb4, 256, 0, stream>>>(h1b, as1v, ad1v, rowptr, csrsrc, b1, out1e, n);

  // h2b/as2/ad2 = gemm2(out1e, W2) fused
  k_gemm2<<<Mpad / 128, 512, 0, stream>>>(out1e, w2th, w2tl, a_src2, a_dst2,
                                          h2b, as2v, ad2v, n);

  // layer-2 attention -> output
  k_agg2<<<nb4, 256, 0, stream>>>(h2b, as2v, ad2v, rowptr, csrsrc, b2, out, n);
}

// Round 15
// 209.758 us; speedup vs baseline: 1.2567x; 1.0123x over previous
//
#include <hip/hip_runtime.h>
#include <math.h>

typedef __attribute__((ext_vector_type(8))) short bf16x8;
typedef __attribute__((ext_vector_type(8))) unsigned short u16x8;
typedef __attribute__((ext_vector_type(4))) float f32x4;

__device__ __forceinline__ float lrelu(float x) { return x > 0.f ? x : 0.2f * x; }

__device__ __forceinline__ unsigned short f2bf(float f) {
  unsigned int u = __float_as_uint(f);
  unsigned int r = (u + 0x7FFFu + ((u >> 16) & 1u)) >> 16;   // RNE
  return (unsigned short)r;
}
__device__ __forceinline__ float bf2f(unsigned short h) {
  return __uint_as_float(((unsigned int)h) << 16);
}

// swizzled LDS offset (in shorts) for [rows][64]bf16 tile: 16B chunk c16 of row
__device__ __forceinline__ int swz(int row, int c16) {
  return (row * 8 + (c16 ^ (row & 7))) * 8;
}

// ---------------- prep: W1/W2 split+transpose + zero degree/fill counters ----------------
__global__ __launch_bounds__(256) void k_prep(const float* __restrict__ W1,
    const float* __restrict__ W2,
    unsigned short* __restrict__ Wth, unsigned short* __restrict__ Wtl,
    unsigned short* __restrict__ W2th, unsigned short* __restrict__ W2tl,
    int* __restrict__ zeros, int nz)
{
  int bid = blockIdx.x, t = threadIdx.x;
  if (bid < 256) {
    float v = W1[t * 256 + bid];
    unsigned short h = f2bf(v);
    Wth[bid * 256 + t] = h;
    Wtl[bid * 256 + t] = f2bf(v - bf2f(h));
  } else {
    int nn = bid - 256;
    float v = W2[t * 32 + nn];
    unsigned short h = f2bf(v);
    W2th[nn * 256 + t] = h;
    W2tl[nn * 256 + t] = f2bf(v - bf2f(h));
  }
  for (int i = bid * 256 + t; i < nz; i += gridDim.x * 256) zeros[i] = 0;
}

// ---------------- GEMM1 mega-kernel: gemm blocks [0,ntiles) + CSR blocks [ntiles,grid) ----------------
// csr_mode 0: degree histogram into cnt. csr_mode 1: CSR fill (cnt=fillc, needs rowptr).
// B fragments double-buffered in registers: next (kt,kk) set issued before current MFMA group.
__global__ __launch_bounds__(512, 4) void k_gemm1(
    const float* __restrict__ X,
    const unsigned short* __restrict__ Bth, const unsigned short* __restrict__ Btl,
    const float* __restrict__ a_src, const float* __restrict__ a_dst,
    unsigned short* __restrict__ h1b, float* __restrict__ as1, float* __restrict__ ad1,
    int M, int tile0, int ntiles, int csr_mode,
    const int* __restrict__ ei, int* __restrict__ cnt,
    const int* __restrict__ rowptr, int* __restrict__ csrsrc, int E, int etot)
{
  __shared__ __align__(16) unsigned short Ah[64 * 64];    // 8KB
  __shared__ __align__(16) unsigned short Al[64 * 64];    // 8KB
  __shared__ __align__(16) unsigned short Cex[8 * 1024];  // 16KB (epilogue, waves 4-7)
  const int t = threadIdx.x;

  // CSR helper blocks: fill free CU slots, run concurrently with GEMM blocks
  if (blockIdx.x >= ntiles) {
    int b = blockIdx.x - ntiles;
    int stride = (gridDim.x - ntiles) * 512;
    if (csr_mode == 0) {
      for (int e = b * 512 + t; e < etot; e += stride) {
        int dst = (e < E) ? ei[E + e] : (e - E);
        atomicAdd(&cnt[dst], 1);
      }
    } else {
      for (int e = b * 512 + t; e < etot; e += stride) {
        int src, dst;
        if (e < E) { src = ei[e]; dst = ei[E + e]; }
        else { src = dst = e - E; }
        int pos = rowptr[dst] + atomicAdd(&cnt[dst], 1);
        csrsrc[pos] = src;
      }
    }
    return;
  }

  const int lane = t & 63;
  const int w = t >> 6;               // wave = head
  const int lrow = lane & 15, lkb = lane >> 4;
  const int brow = (tile0 + blockIdx.x) * 64;

  f32x4 acc[4][2];
#pragma unroll
  for (int i = 0; i < 4; ++i)
#pragma unroll
    for (int j = 0; j < 2; ++j) acc[i][j] = (f32x4){0.f, 0.f, 0.f, 0.f};

  // A prefetch (k-tile 0)
  float4 pref[2];
#pragma unroll
  for (int r = 0; r < 2; ++r) {
    int id = r * 512 + t, m = id >> 4, cq = id & 15, gm = brow + m;
    pref[r] = (gm < M) ? *(const float4*)&X[(size_t)gm * 256 + cq * 4]
                       : make_float4(0.f, 0.f, 0.f, 0.f);
  }

  // B double-buffer: set A = (kt,kk=0), set B = (kt,kk=1); j stride = 16*256
  const size_t bbase = (size_t)(w * 32 + lrow) * 256 + lkb * 8;
  bf16x8 bhA[2], blA[2], bhB[2], blB[2];
#pragma unroll
  for (int j = 0; j < 2; ++j) {
    bhA[j] = *(const bf16x8*)&Bth[bbase + j * 4096];
    blA[j] = *(const bf16x8*)&Btl[bbase + j * 4096];
  }

  for (int kt = 0; kt < 4; ++kt) {
    const int k0 = kt * 64;
#pragma unroll
    for (int r = 0; r < 2; ++r) {
      int id = r * 512 + t, m = id >> 4, cq = id & 15;
      float4 v = pref[r];
      unsigned short h0 = f2bf(v.x), h1 = f2bf(v.y), h2 = f2bf(v.z), h3 = f2bf(v.w);
      unsigned short l0 = f2bf(v.x - bf2f(h0)), l1 = f2bf(v.y - bf2f(h1));
      unsigned short l2 = f2bf(v.z - bf2f(h2)), l3 = f2bf(v.w - bf2f(h3));
      int off = swz(m, cq >> 1) + (cq & 1) * 4;
      *(uint2*)&Ah[off] = make_uint2((unsigned)h0 | ((unsigned)h1 << 16),
                                     (unsigned)h2 | ((unsigned)h3 << 16));
      *(uint2*)&Al[off] = make_uint2((unsigned)l0 | ((unsigned)l1 << 16),
                                     (unsigned)l2 | ((unsigned)l3 << 16));
    }
    if (kt < 3) {
#pragma unroll
      for (int r = 0; r < 2; ++r) {
        int id = r * 512 + t, m = id >> 4, cq = id & 15, gm = brow + m;
        pref[r] = (gm < M) ? *(const float4*)&X[(size_t)gm * 256 + k0 + 64 + cq * 4]
                           : make_float4(0.f, 0.f, 0.f, 0.f);
      }
    }
    __syncthreads();

    // ---- kk = 0: consume set A; issue set B = (kt, kk=1) ----
#pragma unroll
    for (int j = 0; j < 2; ++j) {
      bhB[j] = *(const bf16x8*)&Bth[bbase + k0 + 32 + j * 4096];
      blB[j] = *(const bf16x8*)&Btl[bbase + k0 + 32 + j * 4096];
    }
#pragma unroll
    for (int i = 0; i < 4; ++i) {
      int lo = swz(i * 16 + lrow, lkb);
      bf16x8 ah = *(const bf16x8*)&Ah[lo];
      bf16x8 al = *(const bf16x8*)&Al[lo];
#pragma unroll
      for (int j = 0; j < 2; ++j) {
        acc[i][j] = __builtin_amdgcn_mfma_f32_16x16x32_bf16(ah, bhA[j], acc[i][j], 0, 0, 0);
        acc[i][j] = __builtin_amdgcn_mfma_f32_16x16x32_bf16(ah, blA[j], acc[i][j], 0, 0, 0);
        acc[i][j] = __builtin_amdgcn_mfma_f32_16x16x32_bf16(al, bhA[j], acc[i][j], 0, 0, 0);
      }
    }

    // ---- kk = 1: consume set B; issue set A = (kt+1, kk=0) ----
    if (kt < 3) {
#pragma unroll
      for (int j = 0; j < 2; ++j) {
        bhA[j] = *(const bf16x8*)&Bth[bbase + k0 + 64 + j * 4096];
        blA[j] = *(const bf16x8*)&Btl[bbase + k0 + 64 + j * 4096];
      }
    }
#pragma unroll
    for (int i = 0; i < 4; ++i) {
      int lo = swz(i * 16 + lrow, 4 + lkb);
      bf16x8 ah = *(const bf16x8*)&Ah[lo];
      bf16x8 al = *(const bf16x8*)&Al[lo];
#pragma unroll
      for (int j = 0; j < 2; ++j) {
        acc[i][j] = __builtin_amdgcn_mfma_f32_16x16x32_bf16(ah, bhB[j], acc[i][j], 0, 0, 0);
        acc[i][j] = __builtin_amdgcn_mfma_f32_16x16x32_bf16(ah, blB[j], acc[i][j], 0, 0, 0);
        acc[i][j] = __builtin_amdgcn_mfma_f32_16x16x32_bf16(al, bhB[j], acc[i][j], 0, 0, 0);
      }
    }
    __syncthreads();
  }

  const int c15 = lane & 15, q = lane >> 4;

  // fused as1/ad1 for head w, interleaved [n][8]
  float asv[2], adv[2];
#pragma unroll
  for (int j = 0; j < 2; ++j) {
    int idx = w * 32 + j * 16 + c15;
    asv[j] = a_src[idx];
    adv[j] = a_dst[idx];
  }
#pragma unroll
  for (int i = 0; i < 4; ++i) {
#pragma unroll
    for (int r = 0; r < 4; ++r) {
      int gm = brow + i * 16 + q * 4 + r;
      float pS = acc[i][0][r] * asv[0] + acc[i][1][r] * asv[1];
      float pD = acc[i][0][r] * adv[0] + acc[i][1][r] * adv[1];
#pragma unroll
      for (int off = 1; off < 16; off <<= 1) {
        pS += __shfl_xor(pS, off);
        pD += __shfl_xor(pD, off);
      }
      if (c15 == 0 && gm < M) {
        as1[(size_t)gm * 8 + w] = pS;
        ad1[(size_t)gm * 8 + w] = pD;
      }
    }
  }

  // one-pass C transpose: wave region [64 rows][32 cols] = 4KB; full-line 16B stores
  unsigned short* cst = (w < 4) ? ((w < 2) ? (Ah + w * 2048) : (Al + (w - 2) * 2048))
                                : (Cex + (w - 4) * 2048);
#pragma unroll
  for (int i = 0; i < 4; ++i)
#pragma unroll
    for (int j = 0; j < 2; ++j)
#pragma unroll
      for (int r = 0; r < 4; ++r) {
        int row = i * 16 + q * 4 + r;
        cst[row * 32 + j * 16 + c15] = f2bf(acc[i][j][r]);
      }
#pragma unroll
  for (int t2 = 0; t2 < 4; ++t2) {
    int idx = t2 * 64 + lane;
    int row = idx >> 2, ch = idx & 3;
    u16x8 v = *(const u16x8*)&cst[idx * 8];
    int gm = brow + row;
    if (gm < M)
      *(u16x8*)&h1b[(size_t)gm * 256 + w * 32 + ch * 8] = v;
  }
}

// ---------------- GEMM2 fused: h2b = bf16(out1e @ W2) + as2/ad2 epilogue ----------------
__global__ __launch_bounds__(512) void k_gemm2(
    const unsigned short* __restrict__ Ae,
    const unsigned short* __restrict__ Bth, const unsigned short* __restrict__ Btl,
    const float* __restrict__ a_src, const float* __restrict__ a_dst,
    unsigned short* __restrict__ h2b, float* __restrict__ as2, float* __restrict__ ad2,
    int M)
{
  const int t = threadIdx.x, lane = t & 63, w = t >> 6;
  const int lrow = lane & 15, lkb = lane >> 4;
  const int grow = blockIdx.x * 128 + w * 16;

  f32x4 acc[2];
  acc[0] = (f32x4){0.f, 0.f, 0.f, 0.f};
  acc[1] = (f32x4){0.f, 0.f, 0.f, 0.f};

#pragma unroll
  for (int kt = 0; kt < 4; ++kt) {
    const int k0 = kt * 64;
#pragma unroll
    for (int kk = 0; kk < 2; ++kk) {
      bf16x8 a = *(const bf16x8*)&Ae[(size_t)(grow + lrow) * 256 + k0 + kk * 32 + lkb * 8];
#pragma unroll
      for (int j = 0; j < 2; ++j) {
        size_t g = (size_t)(j * 16 + lrow) * 256 + k0 + kk * 32 + lkb * 8;
        bf16x8 bh = *(const bf16x8*)&Bth[g];
        bf16x8 bl = *(const bf16x8*)&Btl[g];
        acc[j] = __builtin_amdgcn_mfma_f32_16x16x32_bf16(a, bh, acc[j], 0, 0, 0);
        acc[j] = __builtin_amdgcn_mfma_f32_16x16x32_bf16(a, bl, acc[j], 0, 0, 0);
      }
    }
  }

  const int c15 = lane & 15, q = lane >> 4;
  float asv[2] = { a_src[c15], a_src[16 + c15] };
  float adv[2] = { a_dst[c15], a_dst[16 + c15] };
#pragma unroll
  for (int r = 0; r < 4; ++r) {
    int gm = grow + q * 4 + r;
    float pS = acc[0][r] * asv[0] + acc[1][r] * asv[1];
    float pD = acc[0][r] * adv[0] + acc[1][r] * adv[1];
#pragma unroll
    for (int off = 1; off < 16; off <<= 1) {
      pS += __shfl_xor(pS, off);
      pD += __shfl_xor(pD, off);
    }
    if (c15 == 0 && gm < M) { as2[gm] = pS; ad2[gm] = pD; }
    if (gm < M) {
      h2b[(size_t)gm * 32 + c15]      = f2bf(acc[0][r]);
      h2b[(size_t)gm * 32 + 16 + c15] = f2bf(acc[1][r]);
    }
  }
}

// ---------------- CSR scans ----------------
__global__ void k_scan1(const int* __restrict__ deg, int* __restrict__ rowptr,
                        int* __restrict__ bsums, int n)
{
  __shared__ int sm[2][1024];
  int t = threadIdx.x, b = blockIdx.x;
  int i = b * 1024 + t;
  int v = (i < n) ? deg[i] : 0;
  sm[0][t] = v;
  __syncthreads();
  int pb = 0;
  for (int off = 1; off < 1024; off <<= 1) {
    int x = sm[pb][t];
    if (t >= off) x += sm[pb][t - off];
    sm[pb ^ 1][t] = x;
    pb ^= 1;
    __syncthreads();
  }
  if (i < n) rowptr[i] = sm[pb][t] - v;
  if (t == 1023) bsums[b] = sm[pb][1023];
}

__global__ void k_scan23(int* __restrict__ rowptr, const int* __restrict__ bsums,
                         int n, int etot)
{
  int i = blockIdx.x * blockDim.x + threadIdx.x;
  if (i > n) return;
  int b = i >> 10;
  int pre = 0;
  for (int k = 0; k < b; ++k) pre += bsums[k];
  if (i < n) rowptr[i] += pre;
  if (i == 0) rowptr[n] = etot;
}

// ---------------- layer-1 aggregation: wave per node, single pass ----------------
__global__ __launch_bounds__(256) void k_agg1(const unsigned short* __restrict__ h1b,
    const float* __restrict__ as1, const float* __restrict__ ad1,
    const int* __restrict__ rowptr, const int* __restrict__ csrsrc,
    const float* __restrict__ b1, unsigned short* __restrict__ out1e, int n)
{
  __shared__ float alds[4][64][8];
  __shared__ int   slds[4][64];

  int ns = threadIdx.x >> 6;
  int node = blockIdx.x * 4 + ns;
  if (node >= n) return;
  int lane = threadIdx.x & 63;
  int r0 = rowptr[node];
  int deg = rowptr[node + 1] - r0;

  int h = lane & 7;
  int slot = lane >> 3;
  float adv = ad1[node * 8 + h];

  int hh = lane >> 3;
  float s = 0.f;
  float4 acc = make_float4(0.f, 0.f, 0.f, 0.f);

  for (int c0 = 0; c0 < deg; c0 += 64) {
#pragma unroll
    for (int r = 0; r < 8; ++r) {
      int kl = r * 8 + slot;
      int k = c0 + kl;
      if (k < deg) {
        int src = csrsrc[r0 + k];
        float e = fminf(lrelu(as1[src * 8 + h] + adv), 60.f);
        float ex = __expf(e);
        s += ex;
        alds[ns][kl][h] = ex;
        if (h == 0) slds[ns][kl] = src;
      }
    }
    int clen = (deg - c0 < 64) ? (deg - c0) : 64;
#pragma unroll 4
    for (int j = 0; j < clen; ++j) {
      float a = alds[ns][j][hh];
      int src = slds[ns][j];
      ushort4 hv = *(const ushort4*)&h1b[(size_t)src * 256 + lane * 4];
      acc.x = fmaf(a, bf2f(hv.x), acc.x);
      acc.y = fmaf(a, bf2f(hv.y), acc.y);
      acc.z = fmaf(a, bf2f(hv.z), acc.z);
      acc.w = fmaf(a, bf2f(hv.w), acc.w);
    }
  }
#pragma unroll
  for (int off = 8; off < 64; off <<= 1) s += __shfl_xor(s, off);
  float sh = __shfl(s, hh);
  float inv = 1.f / (sh + 1e-16f);

  float4 bv = *(const float4*)&b1[lane * 4];
  float ox = acc.x * inv + bv.x, oy = acc.y * inv + bv.y;
  float oz = acc.z * inv + bv.z, ow = acc.w * inv + bv.w;
  ushort4 ob;
  ob.x = f2bf(ox > 0.f ? ox : expm1f(ox));
  ob.y = f2bf(oy > 0.f ? oy : expm1f(oy));
  ob.z = f2bf(oz > 0.f ? oz : expm1f(oz));
  ob.w = f2bf(ow > 0.f ? ow : expm1f(ow));
  *(ushort4*)&out1e[(size_t)node * 256 + lane * 4] = ob;
}

// ---------------- layer-2 aggregation: 8 lanes/edge, single pass ----------------
__global__ __launch_bounds__(256) void k_agg2(const unsigned short* __restrict__ h2b,
    const float* __restrict__ as2, const float* __restrict__ ad2,
    const int* __restrict__ rowptr, const int* __restrict__ csrsrc,
    const float* __restrict__ b2, float* __restrict__ out, int n)
{
  const int wid = threadIdx.x >> 6;
  const int lane = threadIdx.x & 63;
  const int node = blockIdx.x * 4 + wid;
  if (node >= n) return;

  const int r0 = rowptr[node];
  const int deg = rowptr[node + 1] - r0;
  const float adv = ad2[node];

  const int c4 = lane & 7;
  const int es = lane >> 3;
  float s = 0.f;
  float ax = 0.f, ay = 0.f, az = 0.f, aw = 0.f;

  const int dfull = deg & ~7;
#pragma unroll 2
  for (int c0 = 0; c0 < dfull; c0 += 8) {
    int src = csrsrc[r0 + c0 + es];
    float e = fminf(lrelu(as2[src] + adv), 60.f);
    float ex = __expf(e);
    s += ex;
    ushort4 hv = *(const ushort4*)&h2b[(size_t)src * 32 + c4 * 4];
    ax = fmaf(ex, bf2f(hv.x), ax);
    ay = fmaf(ex, bf2f(hv.y), ay);
    az = fmaf(ex, bf2f(hv.z), az);
    aw = fmaf(ex, bf2f(hv.w), aw);
  }
  if (dfull + es < deg) {
    int src = csrsrc[r0 + dfull + es];
    float e = fminf(lrelu(as2[src] + adv), 60.f);
    float ex = __expf(e);
    s += ex;
    ushort4 hv = *(const ushort4*)&h2b[(size_t)src * 32 + c4 * 4];
    ax = fmaf(ex, bf2f(hv.x), ax);
    ay = fmaf(ex, bf2f(hv.y), ay);
    az = fmaf(ex, bf2f(hv.z), az);
    aw = fmaf(ex, bf2f(hv.w), aw);
  }
#pragma unroll
  for (int off = 8; off < 64; off <<= 1) {
    s  += __shfl_xor(s, off);
    ax += __shfl_xor(ax, off);
    ay += __shfl_xor(ay, off);
    az += __shfl_xor(az, off);
    aw += __shfl_xor(aw, off);
  }
  if (es == 0) {
    float inv = 1.f / (s + 1e-16f);
    float4 o;
    o.x = ax * inv + b2[c4 * 4 + 0];
    o.y = ay * inv + b2[c4 * 4 + 1];
    o.z = az * inv + b2[c4 * 4 + 2];
    o.w = aw * inv + b2[c4 * 4 + 3];
    *(float4*)&out[(size_t)node * 32 + c4 * 4] = o;
  }
}

// ---------------- host launch ----------------
extern "C" void kernel_launch(void* const* d_in, const int* in_sizes, int n_in,
                              void* d_out, int out_size, void* d_ws, size_t ws_size,
                              hipStream_t stream)
{
  const float* x      = (const float*)d_in[0];
  const int*   ei     = (const int*)d_in[1];
  const float* W1     = (const float*)d_in[3];
  const float* a_src1 = (const float*)d_in[4];
  const float* a_dst1 = (const float*)d_in[5];
  const float* b1     = (const float*)d_in[6];
  const float* W2     = (const float*)d_in[7];
  const float* a_src2 = (const float*)d_in[8];
  const float* a_dst2 = (const float*)d_in[9];
  const float* b2     = (const float*)d_in[10];
  float* out = (float*)d_out;

  const int n = in_sizes[0] / 256;            // 50000
  const int E = in_sizes[2];                  // 800000
  const int etot = E + n;                     // 850000
  const int Mpad = ((n + 255) / 256) * 256;   // 50176
  const int NT = Mpad / 64;                   // 784 gemm1 tiles
  const int H1T = 432;                        // half-1 tiles (hosts deg, lighter)
  const int H2T = NT - H1T;                   // 352 (hosts fill, heavier)
  const int CB = 256;                         // CSR helper blocks per half

  // workspace carve
  unsigned short* h1b   = (unsigned short*)d_ws;           // [n][256] bf16 node-major
  unsigned short* out1e = h1b + (size_t)n * 256;           // [Mpad][256] bf16
  unsigned short* h2b   = out1e + (size_t)Mpad * 256;      // n*32 bf16
  float* as1v = (float*)(h2b + (size_t)n * 32);            // [n][8]
  float* ad1v = as1v + (size_t)n * 8;                      // [n][8]
  float* as2v = ad1v + (size_t)n * 8;                      // n
  float* ad2v = as2v + n;                                  // n
  int* rowptr = (int*)(ad2v + n);                          // n+1
  int* degc   = rowptr + (n + 1);                          // n
  int* fillc  = degc + n;                                  // n
  int* csrsrc = fillc + n;                                 // etot
  int* bsums  = csrsrc + etot;                             // <=64
  unsigned short* wth  = (unsigned short*)(bsums + 64);    // 65536
  unsigned short* wtl  = wth + 65536;                      // 65536
  unsigned short* w2th = wtl + 65536;                      // 8192
  unsigned short* w2tl = w2th + 8192;                      // 8192

  // prep: weight splits + zero degc/fillc (2n ints)
  k_prep<<<288, 256, 0, stream>>>(W1, W2, wth, wtl, w2th, w2tl, degc, 2 * n);

  // half 1: gemm1 tiles [0, H1T) || degree histogram
  k_gemm1<<<H1T + CB, 512, 0, stream>>>(x, wth, wtl, a_src1, a_dst1,
                                        h1b, as1v, ad1v, n, 0, H1T, 0,
                                        ei, degc, nullptr, csrsrc, E, etot);

  // CSR scans
  int nblk = (n + 1023) / 1024;
  k_scan1<<<nblk, 1024, 0, stream>>>(degc, rowptr, bsums, n);
  k_scan23<<<(n + 256) / 256, 256, 0, stream>>>(rowptr, bsums, n, etot);

  // half 2: gemm1 tiles [H1T, NT) || CSR fill
  k_gemm1<<<H2T + CB, 512, 0, stream>>>(x, wth, wtl, a_src1, a_dst1,
                                        h1b, as1v, ad1v, n, H1T, H2T, 1,
                                        ei, fillc, rowptr, csrsrc, E, etot);

  // layer-1 attention (wave per node, all heads, single pass)
  int nb4 = (n + 3) / 4;
  k_agg1<<<nb4, 256, 0, stream>>>(h1b, as1v, ad1v, rowptr, csrsrc, b1, out1e, n);

  // h2b/as2/ad2 = gemm2(out1e, W2) fused
  k_gemm2<<<Mpad / 128, 512, 0, stream>>>(out1e, w2th, w2tl, a_src2, a_dst2,
                                          h2b, as2v, ad2v, n);

  // layer-2 attention -> output
  k_agg2<<<nb4, 256, 0, stream>>>(h2b, as2v, ad2v, rowptr, csrsrc, b2, out, n);
}